// Round 5
// baseline (9900.890 us; speedup 1.0000x reference)
//
#include <hip/hip_runtime.h>
#include <math.h>

#define BN_EPS 1e-5f

typedef _Float16 f16x8 __attribute__((ext_vector_type(8)));
typedef _Float16 f16x4 __attribute__((ext_vector_type(4)));
typedef unsigned short u16x8 __attribute__((ext_vector_type(8)));
typedef float f32x4 __attribute__((ext_vector_type(4)));
typedef float f32x16 __attribute__((ext_vector_type(16)));

// ---------------------------------------------------------------------------
// Workspace (float offsets):
//  We     @ 0         (5376)
//  be     @ 8192      (64)
//  W2     @ 12288     (65536)
//  A      @ 81920     (262144)
//  Abias  @ 344064    (4096)
//  WeF    @ 348160    (3072 fl = 6144 halves)
//  Apk    @ 352256    (131072 fl = 262144 halves)
//  Wcv    @ 483328    (82944 fl = 165888 halves) [gate3][kch3][tap9][m4][lane64][8]
//  sixf   @ 566272    (33554432 fl) [blk1024][t8][b2][slot2][ch128][p16] u16/f16
//  h16    @ 34120704  (2097152 fl)  [blk][b2][p][ch] f16
//  cstate @ 36217856  (4194304 fl)  [blk][p16][b2*128+ch]
//  end 40412160 fl = 161.6 MB
// ---------------------------------------------------------------------------

__global__ void prep_enc_w(const float* __restrict__ conv1d_w,
                           const float* __restrict__ conv1d_b,
                           const float* __restrict__ gamma,
                           const float* __restrict__ beta,
                           const float* __restrict__ mean,
                           const float* __restrict__ var,
                           float* __restrict__ We, float* __restrict__ be) {
  int tid = blockIdx.x * blockDim.x + threadIdx.x;
  if (tid < 5376) {
    int c = tid / 84, f = tid % 84;
    float s = gamma[c] * rsqrtf(var[c] + BN_EPS);
    We[c * 84 + f] = s * conv1d_w[c * 252 + f * 3 + 1];
    if (f == 0) be[c] = s * conv1d_b[c] + (beta[c] - mean[c] * s);
  }
}

__global__ void prep_wef(const float* __restrict__ We, _Float16* __restrict__ WeF) {
  int tid = blockIdx.x * blockDim.x + threadIdx.x;  // 6144
  if (tid >= 6144) return;
  int j = tid & 7, lane = (tid >> 3) & 63, kch = (tid >> 9) % 3, ct = tid / 1536;
  int c = ct * 16 + (lane & 15);
  int k = kch * 32 + (lane >> 4) * 8 + j;
  WeF[tid] = (k < 84) ? (_Float16)We[c * 84 + k] : (_Float16)0.f;
}

__global__ void prep_w2(const float* __restrict__ lin_w, float* __restrict__ W2) {
  int tid = blockIdx.x * blockDim.x + threadIdx.x;  // 65536
  int o2 = tid >> 6, c = tid & 63;
  float s = 0.f;
#pragma unroll
  for (int j = 0; j < 16; ++j) s += lin_w[o2 * 1024 + c * 16 + j];
  W2[o2 * 64 + c] = s;
}

__global__ void prep_A(const float* __restrict__ cell_w,
                       const float* __restrict__ cell_b,
                       const float* __restrict__ lin_b,
                       const float* __restrict__ W2,
                       float* __restrict__ A, float* __restrict__ Abias) {
  int tid = blockIdx.x * blockDim.x + threadIdx.x;  // 262144
  int go = tid >> 10;
  int c = (tid >> 4) & 63;
  int p = tid & 15;
  int y = p >> 2, x = p & 3;
  int kn = (go >= 128) ? 16 : 48;
  int xb = (go >= 128) ? 48 : 0;
  float a = 0.f;
  for (int k = 0; k < kn; ++k)
    for (int dy = 0; dy < 3; ++dy) {
      int yy = y + dy - 1;
      if (yy < 0 || yy > 3) continue;
      for (int dx = 0; dx < 3; ++dx) {
        int xx = x + dx - 1;
        if (xx < 0 || xx > 3) continue;
        a += cell_w[((go * 48 + k) * 3 + dy) * 3 + dx] *
             W2[((xb + k) * 16 + yy * 4 + xx) * 64 + c];
      }
    }
  A[(go * 64 + c) * 16 + p] = a;
  if (c == 0) {
    float bs = cell_b[go];
    for (int k = 0; k < kn; ++k)
      for (int dy = 0; dy < 3; ++dy) {
        int yy = y + dy - 1;
        if (yy < 0 || yy > 3) continue;
        for (int dx = 0; dx < 3; ++dx) {
          int xx = x + dx - 1;
          if (xx < 0 || xx > 3) continue;
          bs += cell_w[((go * 48 + k) * 3 + dy) * 3 + dx] *
                lin_b[(xb + k) * 16 + yy * 4 + xx];
        }
      }
    Abias[go * 16 + p] = bs;
  }
}

__global__ void pack_a16(const float* __restrict__ A, _Float16* __restrict__ Apk) {
  int tid = blockIdx.x * blockDim.x + threadIdx.x;  // 262144
  int j = tid & 7, lane = (tid >> 3) & 63, kch = (tid >> 9) & 1, go = tid >> 10;
  int p = lane & 15;
  int c = kch * 32 + (lane >> 4) * 8 + j;
  Apk[tid] = (_Float16)A[(go * 64 + c) * 16 + p];
}

// Wcv uniform: [gate][kch3][tap9][m][lane][8]; gate f (0) kch2 zero-padded.
__global__ void pack_wcv(const float* __restrict__ cell_w, _Float16* __restrict__ Wcv) {
  int tid = blockIdx.x * blockDim.x + threadIdx.x;  // 165888
  if (tid >= 165888) return;
  int j = tid & 7, lane = (tid >> 3) & 63, m = (tid >> 9) & 3;
  int tmp = tid >> 11;
  int tap = tmp % 9, tmp2 = tmp / 9;
  int kch = tmp2 % 3, gate = tmp2 / 3;
  int co = m * 32 + (lane & 31);
  int cil = kch * 16 + (lane >> 5) * 8 + j;  // 0..47
  float v = 0.f;
  if (gate == 0) {
    if (cil < 32) v = cell_w[((size_t)(128 + co) * 48 + 16 + cil) * 9 + tap];
  } else if (gate == 1) {
    v = cell_w[((size_t)(256 + co) * 48 + cil) * 9 + tap];
  } else {
    v = cell_w[((size_t)(384 + co) * 48 + cil) * 9 + tap];
  }
  Wcv[tid] = (_Float16)v;
}

__device__ __forceinline__ float sigm(float v) {
  return __fdividef(1.f, 1.f + __expf(-v));
}
__device__ __forceinline__ float tanh_fast(float v) {
  return 1.f - __fdividef(2.f, __expf(2.f * v) + 1.f);
}

// ---------------------------------------------------------------------------
// xgate: 512 blocks x 256 thr. block = (half, gq, cq). 128 rows (b,trel).
// ---------------------------------------------------------------------------
__global__ __launch_bounds__(256) void xgate_kernel(
    const float* __restrict__ x, const _Float16* __restrict__ WeF,
    const float* __restrict__ be, const _Float16* __restrict__ Apk,
    const float* __restrict__ Abias, unsigned short* __restrict__ sixf, int tc) {
  __shared__ __align__(16) _Float16 x16[128 * 104];   // 26624 B
  __shared__ __align__(16) _Float16 enc_s[128 * 72];  // 18432 B
  int tid = threadIdx.x, lane = tid & 63, w = tid >> 6;
  int half = blockIdx.x & 1;
  int gq = (blockIdx.x >> 1) >> 6, cq = (blockIdx.x >> 1) & 63;
  int n = lane & 15, kgrp = lane >> 4;

  const float* xb = x + ((size_t)cq * 32 * 128 + (size_t)tc * 8) * 84;
  for (int i = tid; i < 10752; i += 256) {
    int ccl = i / 84, kk = i - ccl * 84;
    int cg = half * 128 + ccl;
    x16[ccl * 104 + kk] = (_Float16)xb[(size_t)(cg >> 3) * 10752 + (cg & 7) * 84 + kk];
  }
  for (int i = tid; i < 2560; i += 256) {
    int ccl = i / 20, kk = 84 + (i - ccl * 20);
    x16[ccl * 104 + kk] = (_Float16)0.f;
  }
  __syncthreads();

  // stage 1: encoder; wave w = ctile
  for (int ct4 = 0; ct4 < 8; ++ct4) {
    f32x4 acc = *(const f32x4*)(be + w * 16 + kgrp * 4);
#pragma unroll
    for (int kch = 0; kch < 3; ++kch)
      acc = __builtin_amdgcn_mfma_f32_16x16x32_f16(
          *(const f16x8*)(WeF + ((w * 3 + kch) * 64 + lane) * 8),
          *(const f16x8*)(&x16[(ct4 * 16 + n) * 104 + kch * 32 + kgrp * 8]),
          acc, 0, 0, 0);
#pragma unroll
    for (int r = 0; r < 4; ++r)
      enc_s[(ct4 * 16 + n) * 72 + w * 16 + kgrp * 4 + r] =
          (_Float16)fmaxf(acc[r], 0.f);
  }
  __syncthreads();

  // stage 2: x-gates; wave go-range gq*64 + w*16
  for (int ct4 = 0; ct4 < 8; ++ct4) {
    int ccl = ct4 * 16 + n;
    int cg = half * 128 + ccl;
    int b = cq * 32 + (cg >> 3), trel = cg & 7;
    unsigned short* dstb =
        sixf + (size_t)(b >> 1) * 65536 + (size_t)(trel * 2 + (b & 1)) * 4096;
#pragma unroll 2
    for (int gol = 0; gol < 16; ++gol) {
      int go = gq * 64 + w * 16 + gol;
      f32x4 acc = *(const f32x4*)(Abias + go * 16 + kgrp * 4);
      acc = __builtin_amdgcn_mfma_f32_16x16x32_f16(
          *(const f16x8*)(Apk + (size_t)go * 1024 + lane * 8),
          *(const f16x8*)(&enc_s[ccl * 72 + kgrp * 8]), acc, 0, 0, 0);
      acc = __builtin_amdgcn_mfma_f32_16x16x32_f16(
          *(const f16x8*)(Apk + (size_t)go * 1024 + 512 + lane * 8),
          *(const f16x8*)(&enc_s[ccl * 72 + 32 + kgrp * 8]), acc, 0, 0, 0);
      int ch = go & 127, slot = go >> 7;
      unsigned short* dst = dstb + slot * 2048 + ch * 16 + kgrp * 4;
      if (slot == 0) {
        unsigned lo = ((unsigned)(sigm(acc[0]) * 65535.f + 0.5f)) |
                      ((unsigned)(sigm(acc[1]) * 65535.f + 0.5f) << 16);
        unsigned hi = ((unsigned)(sigm(acc[2]) * 65535.f + 0.5f)) |
                      ((unsigned)(sigm(acc[3]) * 65535.f + 0.5f) << 16);
        uint2 v = {lo, hi};
        *(uint2*)dst = v;
      } else {
        f16x4 v = {(_Float16)acc[0], (_Float16)acc[1], (_Float16)acc[2],
                   (_Float16)acc[3]};
        *(f16x4*)dst = v;
      }
    }
  }
}

// ---------------------------------------------------------------------------
// recur8: 1024 blocks x 768 thr (12 waves), 2 batches/block, 8 steps.
// LDS 58.5 KB -> 2 blocks/CU. Wave = (gate, m): 27 MFMA/t. 2 barriers/t.
// Cell phase: 512 threads, 8 p each.
// ---------------------------------------------------------------------------
#define HPB 4624   // per-b h_pad bytes (17 rows x 272)
#define HPQ 272
#define ZQ 4352
#define GOFF 9248
#define GROW 528   // per (b,p) G row: 128ch f32 + 16B pad
#define GGATE 16896
#define LDSZ (GOFF + 3 * GGATE)  // 59936

__global__ __launch_bounds__(768, 6) void recur8_kernel(
    const unsigned short* __restrict__ sixf, const _Float16* __restrict__ Wcv,
    const float* __restrict__ cell_b, _Float16* __restrict__ h16,
    float* __restrict__ cstate) {
  __shared__ __align__(16) unsigned char lds[LDSZ];
  const int tid = threadIdx.x, lane = tid & 63, w = tid >> 6;
  const int gate = w >> 2, m = w & 3;
  const int blk = blockIdx.x;

  // h16 -> h_pad
  const unsigned* h16u = (const unsigned*)(h16 + (size_t)blk * 4096);
  for (int i = tid; i < 2048; i += 768) {
    unsigned v = h16u[i];
    int hidx = i * 2;
    int b2 = hidx >> 11, r = hidx & 2047, p = r >> 7, ch = r & 127;
    *(unsigned*)(lds + b2 * HPB + p * HPQ + ch * 2) = v;
  }
  for (int i = tid; i < 256; i += 768) {
    int b2 = i >> 7, ch = i & 127;
    *(unsigned short*)(lds + b2 * HPB + ZQ + ch * 2) = 0;
  }

  // conv constants
  const int col = lane & 31, khalf = lane >> 5;
  const int b2c = col >> 4, p_c = col & 15;
  const int yc = p_c >> 2, xc = p_c & 3;
  unsigned tapbase[9];
#pragma unroll
  for (int dy = 0; dy < 3; ++dy)
#pragma unroll
    for (int dx = 0; dx < 3; ++dx) {
      int qy = yc + dy - 1, qx = xc + dx - 1;
      bool valid = (qy >= 0 && qy < 4 && qx >= 0 && qx < 4);
      tapbase[dy * 3 + dx] =
          (valid ? (unsigned)((qy * 4 + qx) * HPQ) : (unsigned)ZQ) +
          (unsigned)(b2c * HPB + khalf * 16);
    }
  const unsigned cioff = (gate == 0) ? 0u : (gate == 1 ? 64u : 160u);
  const unsigned gdump = GOFF + (unsigned)gate * GGATE +
                         (unsigned)(b2c * 16 + p_c) * GROW +
                         (unsigned)(m * 32 + 4 * khalf) * 4;
  const _Float16* wbase =
      Wcv + (size_t)gate * 55296 + (size_t)m * 512 + (size_t)lane * 8;

  // cell constants (tid < 512): (b2, ch, p-half)
  const int cb2 = tid >> 8, crem = tid & 255;
  const int cch = crem >> 1, cph = (crem & 1) * 8;
  const float cbo = cell_b[256 + cch], cbg = cell_b[384 + cch];
  float* cst = cstate + (size_t)blk * 4096 + cb2 * 128 + cch;
  float c_r[8];
  if (tid < 512) {
#pragma unroll
    for (int p = 0; p < 8; ++p) c_r[p] = cst[(cph + p) * 256];
  }
  const unsigned short* sixf_b =
      sixf + (size_t)blk * 65536 + (size_t)cb2 * 4096 + cch * 16 + cph;
  _Float16* h16w = h16 + (size_t)blk * 4096 + cb2 * 2048 + cch;

  __syncthreads();

  for (int t = 0; t < 8; ++t) {
    u16x8 s0;
    f16x8 x0;
    if (tid < 512) {
      const unsigned short* sp = sixf_b + t * 8192;
      s0 = *(const u16x8*)(sp);
      x0 = *(const f16x8*)(sp + 2048);
    }
    // conv phase: 27 MFMA per wave
    f32x16 acc = {};
#pragma unroll
    for (int kt = 0; kt < 27; ++kt) {
      const int kch = kt / 9, tap = kt % 9;
      acc = __builtin_amdgcn_mfma_f32_32x32x16_f16(
          *(const f16x8*)(wbase + (size_t)kt * 2048),
          *(const f16x8*)(lds + tapbase[tap] + cioff + (unsigned)kch * 32),
          acc, 0, 0, 0);
    }
#pragma unroll
    for (int g4 = 0; g4 < 4; ++g4) {
      f32x4 v = {acc[4 * g4], acc[4 * g4 + 1], acc[4 * g4 + 2], acc[4 * g4 + 3]};
      *(f32x4*)(lds + gdump + (unsigned)g4 * 32) = v;
    }
    __syncthreads();
    if (tid < 512) {
      bool lastT = (t == 7);
#pragma unroll
      for (int pp = 0; pp < 8; ++pp) {
        int p = cph + pp;
        float gf = *(const float*)(lds + GOFF + 0 * GGATE +
                                   (cb2 * 16 + p) * GROW + cch * 4);
        float go_ = *(const float*)(lds + GOFF + 1 * GGATE +
                                    (cb2 * 16 + p) * GROW + cch * 4);
        float gg = *(const float*)(lds + GOFF + 2 * GGATE +
                                   (cb2 * 16 + p) * GROW + cch * 4);
        float si = (float)s0[pp] * (1.f / 65535.f);
        float xf = (float)x0[pp];
        float cv = sigm(xf + gf) * c_r[pp] + si * tanh_fast(cbg + gg);
        c_r[pp] = cv;
        float hn = sigm(cbo + go_) * tanh_fast(cv);
        *(_Float16*)(lds + cb2 * HPB + p * HPQ + cch * 2) = (_Float16)hn;
        if (lastT) h16w[p * 128] = (_Float16)hn;
      }
    }
    __syncthreads();
  }
  if (tid < 512) {
#pragma unroll
    for (int p = 0; p < 8; ++p) cst[(cph + p) * 256] = c_r[p];
  }
}

__global__ __launch_bounds__(128) void cls_kernel(
    const _Float16* __restrict__ h16, const float* __restrict__ w1,
    const float* __restrict__ b1, const float* __restrict__ w2,
    const float* __restrict__ b2, float* __restrict__ out) {
  __shared__ __align__(16) float feat[8 * 2064];
  __shared__ float hid[8 * 128];
  int b0 = blockIdx.x * 8;
  for (int i = threadIdx.x; i < 16384; i += 128) {
    int bl = i >> 11, r = i & 2047, p = r >> 7, chh = r & 127;
    feat[bl * 2064 + chh * 16 + p] = (float)h16[(size_t)b0 * 2048 + i];
  }
  __syncthreads();
  int ch = threadIdx.x;
  float acc[8];
#pragma unroll
  for (int b = 0; b < 8; ++b) acc[b] = b1[ch];
  const float4* wr = (const float4*)(w1 + (size_t)ch * 2048);
  for (int k4 = 0; k4 < 512; ++k4) {
    float4 wv = wr[k4];
#pragma unroll
    for (int b = 0; b < 8; ++b) {
      float4 f = *(const float4*)(&feat[b * 2064 + k4 * 4]);
      acc[b] += wv.x * f.x + wv.y * f.y + wv.z * f.z + wv.w * f.w;
    }
  }
#pragma unroll
  for (int b = 0; b < 8; ++b) hid[b * 128 + ch] = fmaxf(acc[b], 0.f);
  __syncthreads();
  if (threadIdx.x < 16) {
    int b = threadIdx.x >> 1, o = threadIdx.x & 1;
    float s = b2[o];
    for (int k = 0; k < 128; ++k) s += hid[b * 128 + k] * w2[o * 128 + k];
    out[(size_t)(b0 + b) * 2 + o] = s;
  }
}

extern "C" void kernel_launch(void* const* d_in, const int* in_sizes, int n_in,
                              void* d_out, int out_size, void* d_ws, size_t ws_size,
                              hipStream_t stream) {
  const float* x        = (const float*)d_in[0];
  const float* conv1d_w = (const float*)d_in[1];
  const float* conv1d_b = (const float*)d_in[2];
  const float* bn_gamma = (const float*)d_in[3];
  const float* bn_beta  = (const float*)d_in[4];
  const float* bn_mean  = (const float*)d_in[5];
  const float* bn_var   = (const float*)d_in[6];
  const float* lin_w    = (const float*)d_in[7];
  const float* lin_b    = (const float*)d_in[8];
  const float* cell_w   = (const float*)d_in[9];
  const float* cell_b   = (const float*)d_in[10];
  const float* cls1_w   = (const float*)d_in[11];
  const float* cls1_b   = (const float*)d_in[12];
  const float* cls2_w   = (const float*)d_in[13];
  const float* cls2_b   = (const float*)d_in[14];

  float* ws = (float*)d_ws;
  float* We    = ws + 0;
  float* be    = ws + 8192;
  float* W2    = ws + 12288;
  float* A     = ws + 81920;
  float* Abias = ws + 344064;
  _Float16* WeF = (_Float16*)(ws + 348160);
  _Float16* Apk = (_Float16*)(ws + 352256);
  _Float16* Wcv = (_Float16*)(ws + 483328);
  unsigned short* sixf = (unsigned short*)(ws + 566272);
  _Float16* h16 = (_Float16*)(ws + 34120704);
  float* cstate = ws + 36217856;
  float* out = (float*)d_out;

  prep_enc_w<<<21, 256, 0, stream>>>(conv1d_w, conv1d_b, bn_gamma, bn_beta,
                                     bn_mean, bn_var, We, be);
  prep_wef<<<24, 256, 0, stream>>>(We, WeF);
  prep_w2<<<256, 256, 0, stream>>>(lin_w, W2);
  prep_A<<<1024, 256, 0, stream>>>(cell_w, cell_b, lin_b, W2, A, Abias);
  pack_a16<<<1024, 256, 0, stream>>>(A, Apk);
  pack_wcv<<<648, 256, 0, stream>>>(cell_w, Wcv);
  hipMemsetAsync(h16, 0, 8388608, stream);
  hipMemsetAsync(cstate, 0, 16777216, stream);
  for (int tc = 0; tc < 16; ++tc) {
    xgate_kernel<<<512, 256, 0, stream>>>(x, WeF, be, Apk, Abias, sixf, tc);
    recur8_kernel<<<1024, 768, 0, stream>>>(sixf, Wcv, cell_b, h16, cstate);
  }
  cls_kernel<<<256, 128, 0, stream>>>(h16, cls1_w, cls1_b, cls2_w, cls2_b, out);
}